// Round 14
// baseline (690.709 us; speedup 1.0000x reference)
//
#include <hip/hip_runtime.h>
#include <hip/hip_bf16.h>

typedef __hip_bfloat16 bf16;
typedef __attribute__((ext_vector_type(8))) short short8;
typedef __attribute__((ext_vector_type(4))) float f32x4;

static constexpr int N_NODES  = 50000;
static constexpr int N_EDGES  = 800000;
static constexpr int F_IN     = 128;
static constexpr int D_HID    = 128;
static constexpr int H_HEADS  = 3;
static constexpr int F_OUT    = 40;
static constexpr float BN_EPS = 1e-5f;
static constexpr float SLOPE  = 0.2f;

__device__ __forceinline__ float bfLo(unsigned int u) { return __uint_as_float(u << 16); }
__device__ __forceinline__ float bfHi(unsigned int u) { return __uint_as_float(u & 0xffff0000u); }
__device__ __forceinline__ unsigned int packbf(float a, float b) {
  union { bf16 h[2]; unsigned int u; } pk;
  pk.h[0] = __float2bfloat16(a);
  pk.h[1] = __float2bfloat16(b);
  return pk.u;
}

// ------- MFMA GEMM 128x128 tile, 4 waves (2x2), 4x4 acc + el/er epilogue ----
__global__ __launch_bounds__(256) void gemm_mfma(const short* __restrict__ A,
                                                 const short* __restrict__ WT,
                                                 bf16* __restrict__ C,
                                                 const float* __restrict__ alp,
                                                 const float* __restrict__ arp,
                                                 float* __restrict__ el,
                                                 float* __restrict__ er,
                                                 int M, int K, int Nc, int els, int ers) {
  constexpr int BM = 128, BN = 128, BK = 64, LDP = BK + 8;  // 72 shorts
  __shared__ short As[BM * LDP];
  __shared__ short Bs[BN * LDP];
  int tid = threadIdx.x;
  int wave = tid >> 6, lane = tid & 63;
  int bm = blockIdx.y, bn = blockIdx.x;
  int m15 = lane & 15, quad = lane >> 4;
  int ksub = quad * 8;
  int wr = wave >> 1, wc = wave & 1;
  int srow = tid >> 3;          // 0..31
  int scol = (tid & 7) * 8;     // 0..56

  f32x4 acc[4][4];
#pragma unroll
  for (int i = 0; i < 4; ++i)
#pragma unroll
    for (int j = 0; j < 4; ++j) acc[i][j] = (f32x4){0.f, 0.f, 0.f, 0.f};

  for (int k0 = 0; k0 < K; k0 += BK) {
#pragma unroll
    for (int c = 0; c < 4; ++c) {
      int r = srow + c * 32;
      int gr = bm * BM + r; if (gr >= M) gr = M - 1;
      *(short8*)&As[r * LDP + scol] = *(const short8*)&A[(size_t)gr * K + k0 + scol];
      int gn = bn * BN + r;   // WT padded to BN rows
      *(short8*)&Bs[r * LDP + scol] = *(const short8*)&WT[(size_t)gn * K + k0 + scol];
    }
    __syncthreads();
#pragma unroll
    for (int ks = 0; ks < BK; ks += 32) {
      short8 a[4], b[4];
#pragma unroll
      for (int i = 0; i < 4; ++i)
        a[i] = *(const short8*)&As[(wr * 64 + i * 16 + m15) * LDP + ks + ksub];
#pragma unroll
      for (int j = 0; j < 4; ++j)
        b[j] = *(const short8*)&Bs[(wc * 64 + j * 16 + m15) * LDP + ks + ksub];
#pragma unroll
      for (int i = 0; i < 4; ++i)
#pragma unroll
        for (int j = 0; j < 4; ++j)
          acc[i][j] = __builtin_amdgcn_mfma_f32_16x16x32_bf16(a[i], b[j], acc[i][j], 0, 0, 0);
    }
    __syncthreads();
  }

  int h = (bn * BN) >> 7;
  float alv[4], arv[4];
#pragma unroll
  for (int j = 0; j < 4; ++j) {
    int col = bn * BN + wc * 64 + j * 16 + m15;
    alv[j] = alp[col];
    arv[j] = arp[col];
  }
#pragma unroll
  for (int i = 0; i < 4; ++i) {
#pragma unroll
    for (int r = 0; r < 4; ++r) {
      int row = bm * BM + wr * 64 + i * 16 + quad * 4 + r;
      float pe = 0.f, pr = 0.f;
#pragma unroll
      for (int j = 0; j < 4; ++j) {
        float v = acc[i][j][r];
        pe += v * alv[j];
        pr += v * arv[j];
        int col = bn * BN + wc * 64 + j * 16 + m15;
        if (row < M && col < Nc)
          C[(size_t)row * Nc + col] = __float2bfloat16(v);
      }
#pragma unroll
      for (int off = 1; off < 16; off <<= 1) {
        pe += __shfl_xor(pe, off);
        pr += __shfl_xor(pr, off);
      }
      if (m15 == 0 && row < M) {
        atomicAdd(&el[(size_t)row * els + h], pe);
        atomicAdd(&er[(size_t)row * ers + h], pr);
      }
    }
  }
}

// ------------- prep: cast x, build WT0/1/2, pad al2/ar2, zero cnt/el/er -----
__global__ void prep_kernel(const float* __restrict__ x, bf16* __restrict__ abuf,
                            const float* __restrict__ W0, const float* __restrict__ W1,
                            const float* __restrict__ W2, bf16* __restrict__ WT0,
                            bf16* __restrict__ WT1, bf16* __restrict__ WT2,
                            const float* __restrict__ al2, const float* __restrict__ ar2,
                            float* __restrict__ alp2, float* __restrict__ arp2,
                            int* __restrict__ cnt, float* __restrict__ elbuf,
                            float* __restrict__ er) {
  const int NTOT = N_NODES * F_IN;  // 6.4M
  for (int i = blockIdx.x * blockDim.x + threadIdx.x; i < NTOT;
       i += gridDim.x * blockDim.x) {
    abuf[i] = __float2bfloat16(x[i]);
    if (i < 384 * 384) { int n = i / 384, k = i - n * 384; WT1[i] = __float2bfloat16(W1[(size_t)k * 384 + n]); }
    if (i < 384 * 128) { int n = i / 128, k = i - n * 128; WT0[i] = __float2bfloat16(W0[(size_t)k * 384 + n]); }
    if (i < 128 * 384) { int n = i / 384, k = i - n * 384; WT2[i] = __float2bfloat16(n < F_OUT ? W2[(size_t)k * F_OUT + n] : 0.f); }
    if (i < 2 * N_NODES) cnt[i] = 0;
    if (i < 4 * N_NODES) elbuf[i] = 0.f;
    if (i < 3 * N_NODES) er[i] = 0.f;
    if (i < 128) { alp2[i] = i < F_OUT ? al2[i] : 0.f; arp2[i] = i < F_OUT ? ar2[i] : 0.f; }
  }
}

// ------------- CSR build ----------------------------------------------------
__global__ void hist_kernel(const int* __restrict__ dst, int* __restrict__ cnt, int E) {
  int i = blockIdx.x * blockDim.x + threadIdx.x;
  if (i < E) atomicAdd(cnt + dst[i], 1);
}

__global__ void scan_part_kernel(const int* __restrict__ cnt, int* __restrict__ blksum, int N) {
  __shared__ int sh[256];
  int i = blockIdx.x * 256 + threadIdx.x;
  sh[threadIdx.x] = (i < N) ? cnt[i] : 0;
  __syncthreads();
  for (int off = 128; off > 0; off >>= 1) {
    if (threadIdx.x < off) sh[threadIdx.x] += sh[threadIdx.x + off];
    __syncthreads();
  }
  if (threadIdx.x == 0) blksum[blockIdx.x] = sh[0];
}

// fused top-scan (redundant per block) + per-block write
__global__ void scan_write_kernel(const int* __restrict__ cnt, const int* __restrict__ blksum,
                                  int* __restrict__ row_ptr, int N, int E, int nblk) {
  __shared__ int top[256];
  __shared__ int sh[256];
  int t = threadIdx.x;
  int vt = (t < nblk) ? blksum[t] : 0;
  top[t] = vt;
  __syncthreads();
  for (int off = 1; off < 256; off <<= 1) {
    int u = (t >= off) ? top[t - off] : 0;
    __syncthreads();
    top[t] += u;
    __syncthreads();
  }
  int blkoff = (blockIdx.x == 0) ? 0 : top[blockIdx.x - 1];
  int i = blockIdx.x * 256 + t;
  int v = (i < N) ? cnt[i] : 0;
  sh[t] = v;
  __syncthreads();
  for (int off = 1; off < 256; off <<= 1) {
    int u = (t >= off) ? sh[t - off] : 0;
    __syncthreads();
    sh[t] += u;
    __syncthreads();
  }
  if (i < N) row_ptr[i] = blkoff + sh[t] - v;
  if (i == 0) row_ptr[N] = E;
}

__global__ void scatter_kernel(const int* __restrict__ src, const int* __restrict__ dst,
                               const int* __restrict__ row_ptr, int* __restrict__ fill,
                               int* __restrict__ csr_src, int E) {
  int i = blockIdx.x * blockDim.x + threadIdx.x;
  if (i < E) {
    int d = dst[i];
    int pos = row_ptr[d] + atomicAdd(fill + d, 1);
    csr_src[pos] = src[i];
  }
}

// ------------- fused aggregation: wave per dst, dwordx4 gather (r12 best) ---
template <int H, int D>  // H=3, D=128 -> 192 words, 48 uint4
__global__ __launch_bounds__(256) void aggr_fused_kernel(
    const int* __restrict__ row_ptr, const int* __restrict__ csr_src,
    const float4* __restrict__ el4, const float* __restrict__ er,
    const bf16* __restrict__ f, uint4* __restrict__ outq,
    float* __restrict__ bnzero, int N) {
  if (blockIdx.x == 0) {
    for (int j = threadIdx.x; j < 2 * H * D; j += 256) bnzero[j] = 0.f;
  }
  constexpr int W = H * D / 2;   // 192 words
  constexpr int WQ = W / 4;      // 48 uint4 per row
  __shared__ float wls[4][64 * H];
  int wv = threadIdx.x >> 6;
  int d = (blockIdx.x * 256 + threadIdx.x) >> 6;
  int lane = threadIdx.x & 63;
  if (d >= N) return;
  int beg = row_ptr[d], end = row_ptr[d + 1];
  const uint4* fq = (const uint4*)f;
  float* mywls = wls[wv];
  int hsel = lane >> 4;  // 0..2 for gather lanes (<48)

  float erd[H];
#pragma unroll
  for (int h = 0; h < H; ++h) erd[h] = er[d * H + h];
  float acc[8];
#pragma unroll
  for (int j = 0; j < 8; ++j) acc[j] = 0.f;
  float sp[H];
#pragma unroll
  for (int h = 0; h < H; ++h) sp[h] = 0.f;

  for (int k0 = beg; k0 < end; k0 += 64) {
    int nk = end - k0; if (nk > 64) nk = 64;
    int s_l = 0;
    if (lane < nk) {
      s_l = csr_src[k0 + lane];
      float4 e4 = el4[s_l];
      float ev[3] = {e4.x, e4.y, e4.z};
#pragma unroll
      for (int h = 0; h < H; ++h) {
        float sc = ev[h] + erd[h];
        sc = sc > 0.f ? sc : SLOPE * sc;
        float w = __expf(sc);
        mywls[lane * H + h] = w;
        sp[h] += w;
      }
    }
    for (int e = 0; e < nk; ++e) {
      int se = __shfl(s_l, e);
      if (lane < WQ) {
        float w = mywls[e * H + hsel];
        uint4 u = fq[(size_t)se * WQ + lane];
        acc[0] += w * bfLo(u.x); acc[1] += w * bfHi(u.x);
        acc[2] += w * bfLo(u.y); acc[3] += w * bfHi(u.y);
        acc[4] += w * bfLo(u.z); acc[5] += w * bfHi(u.z);
        acc[6] += w * bfLo(u.w); acc[7] += w * bfHi(u.w);
      }
    }
  }
#pragma unroll
  for (int h = 0; h < H; ++h) {
#pragma unroll
    for (int off = 32; off > 0; off >>= 1) sp[h] += __shfl_xor(sp[h], off);
  }
  if (lane < WQ) {
    float inv = 1.f / sp[hsel];
    uint4 r;
    r.x = packbf(acc[0] * inv, acc[1] * inv);
    r.y = packbf(acc[2] * inv, acc[3] * inv);
    r.z = packbf(acc[4] * inv, acc[5] * inv);
    r.w = packbf(acc[6] * inv, acc[7] * inv);
    outq[(size_t)d * WQ + lane] = r;
  }
}

// ------------- output-layer aggregation: H=1, D=40, bias fused --------------
__global__ __launch_bounds__(256) void aggr_out_kernel(
    const int* __restrict__ row_ptr, const int* __restrict__ csr_src,
    const float* __restrict__ el, const float* __restrict__ er,
    const bf16* __restrict__ f, const float* __restrict__ bias,
    float* __restrict__ out, int N) {
  constexpr int DW = F_OUT / 2;  // 20 words
  int d = (blockIdx.x * 256 + threadIdx.x) >> 6;
  int lane = threadIdx.x & 63;
  if (d >= N) return;
  int beg = row_ptr[d], end = row_ptr[d + 1];
  const unsigned int* fu = (const unsigned int*)f;
  float erd = er[d];
  float a0 = 0.f, a1 = 0.f, sp = 0.f;
  for (int k0 = beg; k0 < end; k0 += 64) {
    int nk = end - k0; if (nk > 64) nk = 64;
    int s_l = 0; float w_l = 0.f;
    if (lane < nk) {
      s_l = csr_src[k0 + lane];
      float sc = el[s_l] + erd;
      sc = sc > 0.f ? sc : SLOPE * sc;
      w_l = __expf(sc);
      sp += w_l;
    }
    for (int e = 0; e < nk; ++e) {
      int se = __shfl(s_l, e);
      float w = __shfl(w_l, e);
      if (lane < DW) {
        unsigned int u = fu[(size_t)se * DW + lane];
        a0 += w * bfLo(u);
        a1 += w * bfHi(u);
      }
    }
  }
#pragma unroll
  for (int off = 32; off > 0; off >>= 1) sp += __shfl_xor(sp, off);
  if (lane < DW) {
    float inv = 1.f / sp;
    *(float2*)&out[(size_t)d * F_OUT + 2 * lane] =
        make_float2(a0 * inv + bias[2 * lane], a1 * inv + bias[2 * lane + 1]);
  }
}

// ------------- BN stats: 1024 blocks, unroll-4 row loop ---------------------
__global__ void bn_stats_kernel(const unsigned int* __restrict__ h2, float* __restrict__ sum,
                                float* __restrict__ sumsq, int N, int C2) {
  int c = threadIdx.x;  // 0..C2-1 (192)
  int step = gridDim.x;
  float s0 = 0.f, q0 = 0.f, s1 = 0.f, q1 = 0.f;
  int n = blockIdx.x;
  for (; n + 3 * step < N; n += 4 * step) {
    unsigned int ua = h2[(size_t)n * C2 + c];
    unsigned int ub = h2[(size_t)(n + step) * C2 + c];
    unsigned int uc = h2[(size_t)(n + 2 * step) * C2 + c];
    unsigned int ud = h2[(size_t)(n + 3 * step) * C2 + c];
    float va0 = bfLo(ua), va1 = bfHi(ua);
    float vb0 = bfLo(ub), vb1 = bfHi(ub);
    float vc0 = bfLo(uc), vc1 = bfHi(uc);
    float vd0 = bfLo(ud), vd1 = bfHi(ud);
    s0 += va0 + vb0 + vc0 + vd0;
    s1 += va1 + vb1 + vc1 + vd1;
    q0 += va0 * va0 + vb0 * vb0 + vc0 * vc0 + vd0 * vd0;
    q1 += va1 * va1 + vb1 * vb1 + vc1 * vc1 + vd1 * vd1;
  }
  for (; n < N; n += step) {
    unsigned int u = h2[(size_t)n * C2 + c];
    float v0 = bfLo(u), v1 = bfHi(u);
    s0 += v0; q0 += v0 * v0;
    s1 += v1; q1 += v1 * v1;
  }
  atomicAdd(sum + 2 * c, s0);
  atomicAdd(sum + 2 * c + 1, s1);
  atomicAdd(sumsq + 2 * c, q0);
  atomicAdd(sumsq + 2 * c + 1, q1);
}

// ------------- BN apply + ReLU (uint4 = 8 channels/thread) ------------------
__global__ void bn_apply_kernel(const uint4* __restrict__ h4, const float* __restrict__ sum,
                                const float* __restrict__ sumsq, const float* __restrict__ g,
                                const float* __restrict__ be, uint4* __restrict__ out4,
                                float* __restrict__ elz, float* __restrict__ erz,
                                int N, int C) {
  int idx = blockIdx.x * blockDim.x + threadIdx.x;
  if (idx < 4 * N) elz[idx] = 0.f;
  if (idx < 3 * N) erz[idx] = 0.f;
  int total = N * C / 8;
  if (idx >= total) return;
  int c0 = (idx * 8) % C;
  float inv_n = 1.f / (float)N;
  uint4 u = h4[idx];
  unsigned int uw[4] = {u.x, u.y, u.z, u.w};
  unsigned int rw[4];
#pragma unroll
  for (int k = 0; k < 4; ++k) {
    float o[2];
#pragma unroll
    for (int half = 0; half < 2; ++half) {
      int c = c0 + 2 * k + half;
      float v = half ? bfHi(uw[k]) : bfLo(uw[k]);
      float mu = sum[c] * inv_n;
      float var = sumsq[c] * inv_n - mu * mu;
      float val = (v - mu) * rsqrtf(var + BN_EPS) * g[c] + be[c];
      o[half] = val > 0.f ? val : 0.f;
    }
    rw[k] = packbf(o[0], o[1]);
  }
  uint4 r; r.x = rw[0]; r.y = rw[1]; r.z = rw[2]; r.w = rw[3];
  out4[idx] = r;
}

static inline int cdiv(int a, int b) { return (a + b - 1) / b; }

extern "C" void kernel_launch(void* const* d_in, const int* in_sizes, int n_in,
                              void* d_out, int out_size, void* d_ws, size_t ws_size,
                              hipStream_t stream) {
  const float* x   = (const float*)d_in[0];
  const int* src   = (const int*)d_in[1];
  const int* dst   = (const int*)d_in[2];
  const float* W0  = (const float*)d_in[3];
  const float* al0 = (const float*)d_in[4];
  const float* ar0 = (const float*)d_in[5];
  const float* W1  = (const float*)d_in[7];
  const float* al1 = (const float*)d_in[8];
  const float* ar1 = (const float*)d_in[9];
  const float* W2  = (const float*)d_in[11];
  const float* al2 = (const float*)d_in[12];
  const float* ar2 = (const float*)d_in[13];
  const float* b2  = (const float*)d_in[14];
  const float* g0  = (const float*)d_in[15];
  const float* be0 = (const float*)d_in[16];
  const float* g1  = (const float*)d_in[17];
  const float* be1 = (const float*)d_in[18];
  float* out = (float*)d_out;

  const int N = N_NODES, E = N_EDGES, H = H_HEADS;
  const int C = H * D_HID;  // 384
  const int nblk = cdiv(N, 256);  // 196

  // ---- workspace carve ----
  char* p = (char*)d_ws;
  auto take = [&](size_t bytes) {
    char* r = p;
    p += (bytes + 255) & ~(size_t)255;
    return r;
  };
  bf16*   f_buf   = (bf16*) take((size_t)N * C * sizeof(bf16));
  bf16*   hbuf    = (bf16*) take((size_t)N * C * sizeof(bf16));
  bf16*   abuf    = (bf16*) take((size_t)N * C * sizeof(bf16));
  float*  elbuf   = (float*)take((size_t)N * 4 * sizeof(float));
  float*  er      = (float*)take((size_t)N * H * sizeof(float));
  float*  bnbuf   = (float*)take((size_t)2 * C * sizeof(float));  // sum | sumsq
  bf16*   WT0     = (bf16*) take((size_t)C * F_IN * sizeof(bf16));
  bf16*   WT1     = (bf16*) take((size_t)C * C * sizeof(bf16));
  bf16*   WT2     = (bf16*) take((size_t)128 * C * sizeof(bf16)); // 128 rows, zero-padded
  float*  alp2    = (float*)take(128 * sizeof(float));
  float*  arp2    = (float*)take(128 * sizeof(float));
  int*    cnt     = (int*)take((size_t)2 * N * sizeof(int));      // hist | fill
  int*    row_ptr = (int*)take((size_t)(N + 1) * sizeof(int));
  int*    csr_src = (int*)take((size_t)E * sizeof(int));
  int*    blksum  = (int*)take(256 * sizeof(int));
  float*  bnsum = bnbuf, *bnsq = bnbuf + C;
  int*    fill  = cnt + N;

  // ---- prep + CSR build ----
  prep_kernel<<<cdiv(N * F_IN, 256), 256, 0, stream>>>(x, abuf, W0, W1, W2, WT0, WT1, WT2,
                                                       al2, ar2, alp2, arp2, cnt, elbuf, er);
  hist_kernel<<<cdiv(E, 256), 256, 0, stream>>>(dst, cnt, E);
  scan_part_kernel<<<nblk, 256, 0, stream>>>(cnt, blksum, N);
  scan_write_kernel<<<nblk, 256, 0, stream>>>(cnt, blksum, row_ptr, N, E, nblk);
  scatter_kernel<<<cdiv(E, 256), 256, 0, stream>>>(src, dst, row_ptr, fill, csr_src, E);

  // ================= layer 0 =================
  gemm_mfma<<<dim3(C / 128, cdiv(N, 128)), 256, 0, stream>>>(
      (const short*)abuf, (const short*)WT0, f_buf, al0, ar0, elbuf, er, N, F_IN, C, 4, 3);
  aggr_fused_kernel<H_HEADS, D_HID><<<cdiv(N * 64, 256), 256, 0, stream>>>(
      row_ptr, csr_src, (const float4*)elbuf, er, f_buf, (uint4*)hbuf, bnbuf, N);
  bn_stats_kernel<<<1024, C / 2, 0, stream>>>((const unsigned int*)hbuf, bnsum, bnsq, N, C / 2);
  bn_apply_kernel<<<cdiv(N * C / 8, 256), 256, 0, stream>>>(
      (const uint4*)hbuf, bnsum, bnsq, g0, be0, (uint4*)abuf, elbuf, er, N, C);

  // ================= layer 1 =================
  gemm_mfma<<<dim3(C / 128, cdiv(N, 128)), 256, 0, stream>>>(
      (const short*)abuf, (const short*)WT1, f_buf, al1, ar1, elbuf, er, N, C, C, 4, 3);
  aggr_fused_kernel<H_HEADS, D_HID><<<cdiv(N * 64, 256), 256, 0, stream>>>(
      row_ptr, csr_src, (const float4*)elbuf, er, f_buf, (uint4*)hbuf, bnbuf, N);
  bn_stats_kernel<<<1024, C / 2, 0, stream>>>((const unsigned int*)hbuf, bnsum, bnsq, N, C / 2);
  bn_apply_kernel<<<cdiv(N * C / 8, 256), 256, 0, stream>>>(
      (const uint4*)hbuf, bnsum, bnsq, g1, be1, (uint4*)abuf, elbuf, er, N, C);

  // ================= layer 2 (H=1, D=40, bias fused, direct to out) =========
  gemm_mfma<<<dim3(1, cdiv(N, 128)), 256, 0, stream>>>(
      (const short*)abuf, (const short*)WT2, f_buf, alp2, arp2, elbuf, er, N, C, F_OUT, 1, 1);
  aggr_out_kernel<<<cdiv(N * 64, 256), 256, 0, stream>>>(
      row_ptr, csr_src, elbuf, er, f_buf, b2, out, N);
}

// Round 15
// 629.179 us; speedup vs baseline: 1.0978x; 1.0978x over previous
//
#include <hip/hip_runtime.h>
#include <hip/hip_bf16.h>

typedef __hip_bfloat16 bf16;
typedef __attribute__((ext_vector_type(8))) short short8;
typedef __attribute__((ext_vector_type(4))) float f32x4;

static constexpr int N_NODES  = 50000;
static constexpr int N_EDGES  = 800000;
static constexpr int F_IN     = 128;
static constexpr int D_HID    = 128;
static constexpr int H_HEADS  = 3;
static constexpr int F_OUT    = 40;
static constexpr float BN_EPS = 1e-5f;
static constexpr float SLOPE  = 0.2f;

__device__ __forceinline__ float bfLo(unsigned int u) { return __uint_as_float(u << 16); }
__device__ __forceinline__ float bfHi(unsigned int u) { return __uint_as_float(u & 0xffff0000u); }
__device__ __forceinline__ float bfs(unsigned short s) { return __uint_as_float(((unsigned int)s) << 16); }
__device__ __forceinline__ unsigned int packbf(float a, float b) {
  union { bf16 h[2]; unsigned int u; } pk;
  pk.h[0] = __float2bfloat16(a);
  pk.h[1] = __float2bfloat16(b);
  return pk.u;
}
__device__ __forceinline__ short f2bf_s(float v) {
  bf16 h = __float2bfloat16(v);
  union { bf16 b; short s; } c; c.b = h; return c.s;
}

// ------- MFMA GEMM 128x128, fused BN+ReLU on A-staging, el/er direct store --
// If scale != nullptr: A element (bf16) -> max(0, v*scale[c]+shift[c]) -> bf16.
// el/er: one head per 128-col block (BN=128) -> plain store, no zero/atomic.
__global__ __launch_bounds__(256) void gemm_mfma(const short* __restrict__ A,
                                                 const short* __restrict__ WT,
                                                 bf16* __restrict__ C,
                                                 const float* __restrict__ alp,
                                                 const float* __restrict__ arp,
                                                 float* __restrict__ el,
                                                 float* __restrict__ er,
                                                 const float* __restrict__ scale,
                                                 const float* __restrict__ shift,
                                                 int M, int K, int Nc, int els, int ers) {
  constexpr int BM = 128, BN = 128, BK = 64, LDP = BK + 8;
  __shared__ short As[BM * LDP];
  __shared__ short Bs[BN * LDP];
  __shared__ float ecomb[128][4];  // el h0|h1, er h0|h1
  int tid = threadIdx.x;
  int wave = tid >> 6, lane = tid & 63;
  int bm = blockIdx.y, bn = blockIdx.x;
  int m15 = lane & 15, quad = lane >> 4;
  int ksub = quad * 8;
  int wr = wave >> 1, wc = wave & 1;
  int srow = tid >> 3;          // 0..31
  int scol = (tid & 7) * 8;     // 0..56

  f32x4 acc[4][4];
#pragma unroll
  for (int i = 0; i < 4; ++i)
#pragma unroll
    for (int j = 0; j < 4; ++j) acc[i][j] = (f32x4){0.f, 0.f, 0.f, 0.f};

  for (int k0 = 0; k0 < K; k0 += BK) {
    int cb = k0 + scol;
    f32x4 sc0, sc1, sh0, sh1;
    if (scale) {
      sc0 = *(const f32x4*)&scale[cb]; sc1 = *(const f32x4*)&scale[cb + 4];
      sh0 = *(const f32x4*)&shift[cb]; sh1 = *(const f32x4*)&shift[cb + 4];
    }
#pragma unroll
    for (int c = 0; c < 4; ++c) {
      int r = srow + c * 32;
      int gr = bm * BM + r; if (gr >= M) gr = M - 1;
      short8 av = *(const short8*)&A[(size_t)gr * K + k0 + scol];
      if (scale) {
#pragma unroll
        for (int j = 0; j < 8; ++j) {
          float v = bfs((unsigned short)av[j]);
          float s = (j < 4) ? ((const float*)&sc0)[j] : ((const float*)&sc1)[j - 4];
          float t = (j < 4) ? ((const float*)&sh0)[j] : ((const float*)&sh1)[j - 4];
          float y = v * s + t;
          av[j] = f2bf_s(y > 0.f ? y : 0.f);
        }
      }
      *(short8*)&As[r * LDP + scol] = av;
      int gn = bn * BN + r;   // WT padded to BN rows
      *(short8*)&Bs[r * LDP + scol] = *(const short8*)&WT[(size_t)gn * K + k0 + scol];
    }
    __syncthreads();
#pragma unroll
    for (int ks = 0; ks < BK; ks += 32) {
      short8 a[4], b[4];
#pragma unroll
      for (int i = 0; i < 4; ++i)
        a[i] = *(const short8*)&As[(wr * 64 + i * 16 + m15) * LDP + ks + ksub];
#pragma unroll
      for (int j = 0; j < 4; ++j)
        b[j] = *(const short8*)&Bs[(wc * 64 + j * 16 + m15) * LDP + ks + ksub];
#pragma unroll
      for (int i = 0; i < 4; ++i)
#pragma unroll
        for (int j = 0; j < 4; ++j)
          acc[i][j] = __builtin_amdgcn_mfma_f32_16x16x32_bf16(a[i], b[j], acc[i][j], 0, 0, 0);
    }
    __syncthreads();
  }

  int h = bn;  // one head per 128-col block
  float alv[4], arv[4];
#pragma unroll
  for (int j = 0; j < 4; ++j) {
    int col = bn * BN + wc * 64 + j * 16 + m15;
    alv[j] = alp[col];
    arv[j] = arp[col];
  }
#pragma unroll
  for (int i = 0; i < 4; ++i) {
#pragma unroll
    for (int r = 0; r < 4; ++r) {
      int rl = wr * 64 + i * 16 + quad * 4 + r;
      int row = bm * BM + rl;
      float pe = 0.f, pr = 0.f;
#pragma unroll
      for (int j = 0; j < 4; ++j) {
        float v = acc[i][j][r];
        pe += v * alv[j];
        pr += v * arv[j];
        int col = bn * BN + wc * 64 + j * 16 + m15;
        if (row < M && col < Nc)
          C[(size_t)row * Nc + col] = __float2bfloat16(v);
      }
#pragma unroll
      for (int off = 1; off < 16; off <<= 1) {
        pe += __shfl_xor(pe, off);
        pr += __shfl_xor(pr, off);
      }
      if (m15 == 0) {
        ecomb[rl][wc] = pe;
        ecomb[rl][2 + wc] = pr;
      }
    }
  }
  __syncthreads();
  if (tid < 128) {
    int row = bm * BM + tid;
    if (row < M) {
      el[(size_t)row * els + h] = ecomb[tid][0] + ecomb[tid][1];
      er[(size_t)row * ers + h] = ecomb[tid][2] + ecomb[tid][3];
    }
  }
}

// ------------- prep: cast x, build WT0/1/2, pad al2/ar2, zero cnt ----------
__global__ void prep_kernel(const float* __restrict__ x, bf16* __restrict__ abuf,
                            const float* __restrict__ W0, const float* __restrict__ W1,
                            const float* __restrict__ W2, bf16* __restrict__ WT0,
                            bf16* __restrict__ WT1, bf16* __restrict__ WT2,
                            const float* __restrict__ al2, const float* __restrict__ ar2,
                            float* __restrict__ alp2, float* __restrict__ arp2,
                            int* __restrict__ cnt) {
  const int NTOT = N_NODES * F_IN;  // 6.4M
  for (int i = blockIdx.x * blockDim.x + threadIdx.x; i < NTOT;
       i += gridDim.x * blockDim.x) {
    abuf[i] = __float2bfloat16(x[i]);
    if (i < 384 * 384) { int n = i / 384, k = i - n * 384; WT1[i] = __float2bfloat16(W1[(size_t)k * 384 + n]); }
    if (i < 384 * 128) { int n = i / 128, k = i - n * 128; WT0[i] = __float2bfloat16(W0[(size_t)k * 384 + n]); }
    if (i < 128 * 384) { int n = i / 384, k = i - n * 384; WT2[i] = __float2bfloat16(n < F_OUT ? W2[(size_t)k * F_OUT + n] : 0.f); }
    if (i < 2 * N_NODES) cnt[i] = 0;
    if (i < 128) { alp2[i] = i < F_OUT ? al2[i] : 0.f; arp2[i] = i < F_OUT ? ar2[i] : 0.f; }
  }
}

// ------------- CSR build ----------------------------------------------------
__global__ void hist_kernel(const int* __restrict__ dst, int* __restrict__ cnt, int E) {
  int i = blockIdx.x * blockDim.x + threadIdx.x;
  if (i < E) atomicAdd(cnt + dst[i], 1);
}

__global__ void scan_part_kernel(const int* __restrict__ cnt, int* __restrict__ blksum, int N) {
  __shared__ int sh[256];
  int i = blockIdx.x * 256 + threadIdx.x;
  sh[threadIdx.x] = (i < N) ? cnt[i] : 0;
  __syncthreads();
  for (int off = 128; off > 0; off >>= 1) {
    if (threadIdx.x < off) sh[threadIdx.x] += sh[threadIdx.x + off];
    __syncthreads();
  }
  if (threadIdx.x == 0) blksum[blockIdx.x] = sh[0];
}

__global__ void scan_write_kernel(const int* __restrict__ cnt, const int* __restrict__ blksum,
                                  int* __restrict__ row_ptr, int N, int E, int nblk) {
  __shared__ int top[256];
  __shared__ int sh[256];
  int t = threadIdx.x;
  int vt = (t < nblk) ? blksum[t] : 0;
  top[t] = vt;
  __syncthreads();
  for (int off = 1; off < 256; off <<= 1) {
    int u = (t >= off) ? top[t - off] : 0;
    __syncthreads();
    top[t] += u;
    __syncthreads();
  }
  int blkoff = (blockIdx.x == 0) ? 0 : top[blockIdx.x - 1];
  int i = blockIdx.x * 256 + t;
  int v = (i < N) ? cnt[i] : 0;
  sh[t] = v;
  __syncthreads();
  for (int off = 1; off < 256; off <<= 1) {
    int u = (t >= off) ? sh[t - off] : 0;
    __syncthreads();
    sh[t] += u;
    __syncthreads();
  }
  if (i < N) row_ptr[i] = blkoff + sh[t] - v;
  if (i == 0) row_ptr[N] = E;
}

__global__ void scatter_kernel(const int* __restrict__ src, const int* __restrict__ dst,
                               const int* __restrict__ row_ptr, int* __restrict__ fill,
                               int* __restrict__ csr_src, int E) {
  int i = blockIdx.x * blockDim.x + threadIdx.x;
  if (i < E) {
    int d = dst[i];
    int pos = row_ptr[d] + atomicAdd(fill + d, 1);
    csr_src[pos] = src[i];
  }
}

// ------------- fused aggregation: wave per dst, dwordx4 gather --------------
template <int H, int D>  // H=3, D=128 -> 192 words, 48 uint4
__global__ __launch_bounds__(256) void aggr_fused_kernel(
    const int* __restrict__ row_ptr, const int* __restrict__ csr_src,
    const float4* __restrict__ el4, const float* __restrict__ er,
    const bf16* __restrict__ f, uint4* __restrict__ outq,
    float* __restrict__ bnzero, int N) {
  if (blockIdx.x == 0) {
    for (int j = threadIdx.x; j < 2 * H * D; j += 256) bnzero[j] = 0.f;
  }
  constexpr int W = H * D / 2;   // 192 words
  constexpr int WQ = W / 4;      // 48 uint4 per row
  __shared__ float wls[4][64 * H];
  int wv = threadIdx.x >> 6;
  int d = (blockIdx.x * 256 + threadIdx.x) >> 6;
  int lane = threadIdx.x & 63;
  if (d >= N) return;
  int beg = row_ptr[d], end = row_ptr[d + 1];
  const uint4* fq = (const uint4*)f;
  float* mywls = wls[wv];
  int hsel = lane >> 4;  // 0..2 for gather lanes (<48)

  float erd[H];
#pragma unroll
  for (int h = 0; h < H; ++h) erd[h] = er[d * H + h];
  float acc[8];
#pragma unroll
  for (int j = 0; j < 8; ++j) acc[j] = 0.f;
  float sp[H];
#pragma unroll
  for (int h = 0; h < H; ++h) sp[h] = 0.f;

  for (int k0 = beg; k0 < end; k0 += 64) {
    int nk = end - k0; if (nk > 64) nk = 64;
    int s_l = 0;
    if (lane < nk) {
      s_l = csr_src[k0 + lane];
      float4 e4 = el4[s_l];
      float ev[3] = {e4.x, e4.y, e4.z};
#pragma unroll
      for (int h = 0; h < H; ++h) {
        float sc = ev[h] + erd[h];
        sc = sc > 0.f ? sc : SLOPE * sc;
        float w = __expf(sc);
        mywls[lane * H + h] = w;
        sp[h] += w;
      }
    }
    for (int e = 0; e < nk; ++e) {
      int se = __shfl(s_l, e);
      if (lane < WQ) {
        float w = mywls[e * H + hsel];
        uint4 u = fq[(size_t)se * WQ + lane];
        acc[0] += w * bfLo(u.x); acc[1] += w * bfHi(u.x);
        acc[2] += w * bfLo(u.y); acc[3] += w * bfHi(u.y);
        acc[4] += w * bfLo(u.z); acc[5] += w * bfHi(u.z);
        acc[6] += w * bfLo(u.w); acc[7] += w * bfHi(u.w);
      }
    }
  }
#pragma unroll
  for (int h = 0; h < H; ++h) {
#pragma unroll
    for (int off = 32; off > 0; off >>= 1) sp[h] += __shfl_xor(sp[h], off);
  }
  if (lane < WQ) {
    float inv = 1.f / sp[hsel];
    uint4 r;
    r.x = packbf(acc[0] * inv, acc[1] * inv);
    r.y = packbf(acc[2] * inv, acc[3] * inv);
    r.z = packbf(acc[4] * inv, acc[5] * inv);
    r.w = packbf(acc[6] * inv, acc[7] * inv);
    outq[(size_t)d * WQ + lane] = r;
  }
}

// ------------- output-layer aggregation: 3-edge groups, bias fused ----------
__global__ __launch_bounds__(256) void aggr_out_kernel(
    const int* __restrict__ row_ptr, const int* __restrict__ csr_src,
    const float* __restrict__ el, const float* __restrict__ er,
    const bf16* __restrict__ f, const float* __restrict__ bias,
    float* __restrict__ out, int N) {
  constexpr int DW = F_OUT / 2;  // 20 words
  __shared__ float wls[4][64];
  __shared__ int   sls[4][64];
  int wv = threadIdx.x >> 6;
  int d = (blockIdx.x * 256 + threadIdx.x) >> 6;
  int lane = threadIdx.x & 63;
  if (d >= N) return;
  int beg = row_ptr[d], end = row_ptr[d + 1];
  const unsigned int* fu = (const unsigned int*)f;
  float* mywls = wls[wv];
  int* mysls = sls[wv];
  int g = lane / DW;       // 0..2 edge-group (lane 60..63 idle in gather)
  int cch = lane - g * DW; // 0..19 channel-pair
  float erd = er[d];
  float a0 = 0.f, a1 = 0.f, sp = 0.f;
  for (int k0 = beg; k0 < end; k0 += 64) {
    int nk = end - k0; if (nk > 64) nk = 64;
    if (lane < nk) {
      int s_l = csr_src[k0 + lane];
      mysls[lane] = s_l;
      float sc = el[s_l] + erd;
      sc = sc > 0.f ? sc : SLOPE * sc;
      float w = __expf(sc);
      mywls[lane] = w;
      sp += w;
    }
    for (int e0 = 0; e0 < nk; e0 += 3) {
      int e = e0 + g;
      if (g < 3 && e < nk) {
        int se = mysls[e];
        float w = mywls[e];
        unsigned int u = fu[(size_t)se * DW + cch];
        a0 += w * bfLo(u);
        a1 += w * bfHi(u);
      }
    }
  }
#pragma unroll
  for (int off = 32; off > 0; off >>= 1) sp += __shfl_xor(sp, off);
  // reduce the 3 edge-groups
  float b0 = __shfl(a0, (lane + DW) & 63), b1 = __shfl(a1, (lane + DW) & 63);
  float c0 = __shfl(a0, (lane + 2 * DW) & 63), c1 = __shfl(a1, (lane + 2 * DW) & 63);
  if (lane < DW) {
    float inv = 1.f / sp;
    float o0 = (a0 + b0 + c0) * inv + bias[2 * lane];
    float o1 = (a1 + b1 + c1) * inv + bias[2 * lane + 1];
    *(float2*)&out[(size_t)d * F_OUT + 2 * lane] = make_float2(o0, o1);
  }
}

// ------------- BN stats: 1024 blocks, unroll-4 row loop ---------------------
__global__ void bn_stats_kernel(const unsigned int* __restrict__ h2, float* __restrict__ sum,
                                float* __restrict__ sumsq, int N, int C2) {
  int c = threadIdx.x;
  int step = gridDim.x;
  float s0 = 0.f, q0 = 0.f, s1 = 0.f, q1 = 0.f;
  int n = blockIdx.x;
  for (; n + 3 * step < N; n += 4 * step) {
    unsigned int ua = h2[(size_t)n * C2 + c];
    unsigned int ub = h2[(size_t)(n + step) * C2 + c];
    unsigned int uc = h2[(size_t)(n + 2 * step) * C2 + c];
    unsigned int ud = h2[(size_t)(n + 3 * step) * C2 + c];
    float va0 = bfLo(ua), va1 = bfHi(ua);
    float vb0 = bfLo(ub), vb1 = bfHi(ub);
    float vc0 = bfLo(uc), vc1 = bfHi(uc);
    float vd0 = bfLo(ud), vd1 = bfHi(ud);
    s0 += va0 + vb0 + vc0 + vd0;
    s1 += va1 + vb1 + vc1 + vd1;
    q0 += va0 * va0 + vb0 * vb0 + vc0 * vc0 + vd0 * vd0;
    q1 += va1 * va1 + vb1 * vb1 + vc1 * vc1 + vd1 * vd1;
  }
  for (; n < N; n += step) {
    unsigned int u = h2[(size_t)n * C2 + c];
    float v0 = bfLo(u), v1 = bfHi(u);
    s0 += v0; q0 += v0 * v0;
    s1 += v1; q1 += v1 * v1;
  }
  atomicAdd(sum + 2 * c, s0);
  atomicAdd(sum + 2 * c + 1, s1);
  atomicAdd(sumsq + 2 * c, q0);
  atomicAdd(sumsq + 2 * c + 1, q1);
}

// ------------- BN finalize: per-channel scale/shift -------------------------
__global__ void bn_finalize_kernel(const float* __restrict__ sum, const float* __restrict__ sumsq,
                                   const float* __restrict__ g, const float* __restrict__ be,
                                   float* __restrict__ scale, float* __restrict__ shift,
                                   int N, int C) {
  int c = threadIdx.x;
  if (c >= C) return;
  float inv_n = 1.f / (float)N;
  float mu = sum[c] * inv_n;
  float var = sumsq[c] * inv_n - mu * mu;
  float sc = g[c] * rsqrtf(var + BN_EPS);
  scale[c] = sc;
  shift[c] = be[c] - mu * sc;
}

static inline int cdiv(int a, int b) { return (a + b - 1) / b; }

extern "C" void kernel_launch(void* const* d_in, const int* in_sizes, int n_in,
                              void* d_out, int out_size, void* d_ws, size_t ws_size,
                              hipStream_t stream) {
  const float* x   = (const float*)d_in[0];
  const int* src   = (const int*)d_in[1];
  const int* dst   = (const int*)d_in[2];
  const float* W0  = (const float*)d_in[3];
  const float* al0 = (const float*)d_in[4];
  const float* ar0 = (const float*)d_in[5];
  const float* W1  = (const float*)d_in[7];
  const float* al1 = (const float*)d_in[8];
  const float* ar1 = (const float*)d_in[9];
  const float* W2  = (const float*)d_in[11];
  const float* al2 = (const float*)d_in[12];
  const float* ar2 = (const float*)d_in[13];
  const float* b2  = (const float*)d_in[14];
  const float* g0  = (const float*)d_in[15];
  const float* be0 = (const float*)d_in[16];
  const float* g1  = (const float*)d_in[17];
  const float* be1 = (const float*)d_in[18];
  float* out = (float*)d_out;

  const int N = N_NODES, E = N_EDGES, H = H_HEADS;
  const int C = H * D_HID;  // 384
  const int nblk = cdiv(N, 256);  // 196

  // ---- workspace carve ----
  char* p = (char*)d_ws;
  auto take = [&](size_t bytes) {
    char* r = p;
    p += (bytes + 255) & ~(size_t)255;
    return r;
  };
  bf16*   f_buf   = (bf16*) take((size_t)N * C * sizeof(bf16));
  bf16*   hbuf    = (bf16*) take((size_t)N * C * sizeof(bf16));
  bf16*   abuf    = (bf16*) take((size_t)N * C * sizeof(bf16));
  float*  elbuf   = (float*)take((size_t)N * 4 * sizeof(float));
  float*  er      = (float*)take((size_t)N * H * sizeof(float));
  float*  bnbuf   = (float*)take((size_t)2 * C * sizeof(float));  // sum | sumsq
  float*  scbuf   = (float*)take((size_t)2 * C * sizeof(float));  // scale | shift
  bf16*   WT0     = (bf16*) take((size_t)C * F_IN * sizeof(bf16));
  bf16*   WT1     = (bf16*) take((size_t)C * C * sizeof(bf16));
  bf16*   WT2     = (bf16*) take((size_t)128 * C * sizeof(bf16));
  float*  alp2    = (float*)take(128 * sizeof(float));
  float*  arp2    = (float*)take(128 * sizeof(float));
  int*    cnt     = (int*)take((size_t)2 * N * sizeof(int));      // hist | fill
  int*    row_ptr = (int*)take((size_t)(N + 1) * sizeof(int));
  int*    csr_src = (int*)take((size_t)E * sizeof(int));
  int*    blksum  = (int*)take(256 * sizeof(int));
  float*  bnsum = bnbuf, *bnsq = bnbuf + C;
  float*  scv = scbuf, *shv = scbuf + C;
  int*    fill  = cnt + N;

  // ---- prep + CSR build ----
  prep_kernel<<<cdiv(N * F_IN, 256), 256, 0, stream>>>(x, abuf, W0, W1, W2, WT0, WT1, WT2,
                                                       al2, ar2, alp2, arp2, cnt);
  hist_kernel<<<cdiv(E, 256), 256, 0, stream>>>(dst, cnt, E);
  scan_part_kernel<<<nblk, 256, 0, stream>>>(cnt, blksum, N);
  scan_write_kernel<<<nblk, 256, 0, stream>>>(cnt, blksum, row_ptr, N, E, nblk);
  scatter_kernel<<<cdiv(E, 256), 256, 0, stream>>>(src, dst, row_ptr, fill, csr_src, E);

  // ================= layer 0 =================
  gemm_mfma<<<dim3(C / 128, cdiv(N, 128)), 256, 0, stream>>>(
      (const short*)abuf, (const short*)WT0, f_buf, al0, ar0, elbuf, er,
      nullptr, nullptr, N, F_IN, C, 4, 3);
  aggr_fused_kernel<H_HEADS, D_HID><<<cdiv(N * 64, 256), 256, 0, stream>>>(
      row_ptr, csr_src, (const float4*)elbuf, er, f_buf, (uint4*)hbuf, bnbuf, N);
  bn_stats_kernel<<<1024, C / 2, 0, stream>>>((const unsigned int*)hbuf, bnsum, bnsq, N, C / 2);
  bn_finalize_kernel<<<1, C, 0, stream>>>(bnsum, bnsq, g0, be0, scv, shv, N, C);

  // ================= layer 1 (BN0+ReLU fused into A-staging) =================
  gemm_mfma<<<dim3(C / 128, cdiv(N, 128)), 256, 0, stream>>>(
      (const short*)hbuf, (const short*)WT1, f_buf, al1, ar1, elbuf, er,
      scv, shv, N, C, C, 4, 3);
  aggr_fused_kernel<H_HEADS, D_HID><<<cdiv(N * 64, 256), 256, 0, stream>>>(
      row_ptr, csr_src, (const float4*)elbuf, er, f_buf, (uint4*)hbuf, bnbuf, N);
  bn_stats_kernel<<<1024, C / 2, 0, stream>>>((const unsigned int*)hbuf, bnsum, bnsq, N, C / 2);
  bn_finalize_kernel<<<1, C, 0, stream>>>(bnsum, bnsq, g1, be1, scv, shv, N, C);

  // ================= layer 2 (BN1+ReLU fused; direct to out) =================
  gemm_mfma<<<dim3(1, cdiv(N, 128)), 256, 0, stream>>>(
      (const short*)hbuf, (const short*)WT2, f_buf, alp2, arp2, elbuf, er,
      scv, shv, N, C, F_OUT, 1, 1);
  aggr_out_kernel<<<cdiv(N * 64, 256), 256, 0, stream>>>(
      row_ptr, csr_src, elbuf, er, f_buf, b2, out, N);
}